// Round 5
// baseline (83.796 us; speedup 1.0000x reference)
//
#include <hip/hip_runtime.h>
#include <math.h>

#define T_STEPS 1000000
#define BLOCK 1024
#define ITEMS 2
#define CHUNK (BLOCK * ITEMS)               // 2048
#define NB ((T_STEPS + CHUNK - 1) / CHUNK)  // 489
#define NF4 (T_STEPS / 2)                   // 500000 float4 of controls
#define NWAVE (BLOCK / 64)                  // 16

// ---- wave/block scan helpers (fp64, shfl + 16-partial LDS) --------------

__device__ __forceinline__ double waveScanIncl(double v) {
#pragma unroll
    for (int off = 1; off < 64; off <<= 1) {
        double x = __shfl_up(v, off, 64);
        if ((threadIdx.x & 63) >= off) v += x;
    }
    return v;
}

// exclusive prefix over the block's per-thread values; *tot = block total
__device__ __forceinline__ double blockScanEx(double v, double* sw, double* tot) {
    const int lane = threadIdx.x & 63, w = threadIdx.x >> 6;
    double inc = waveScanIncl(v);
    if (lane == 63) sw[w] = inc;
    __syncthreads();
    double woff = 0.0, T = 0.0;
#pragma unroll
    for (int i = 0; i < NWAVE; ++i) {
        double x = sw[i];
        T += x;
        if (i < w) woff += x;
    }
    __syncthreads();
    *tot = T;
    return woff + inc - v;
}

__device__ __forceinline__ double blockSum(double v, double* sw) {
#pragma unroll
    for (int off = 32; off > 0; off >>= 1) v += __shfl_xor(v, off, 64);
    const int lane = threadIdx.x & 63, w = threadIdx.x >> 6;
    if (lane == 0) sw[w] = v;
    __syncthreads();
    double r = 0.0;
#pragma unroll
    for (int i = 0; i < NWAVE; ++i) r += sw[i];
    __syncthreads();
    return r;
}

// fp64 range reduction -> HW v_sin_f32/v_cos_f32 (abs err ~1e-6)
__device__ __forceinline__ void ftrig(double th, double& cs, double& sn) {
    const double INV2PI = 0.15915494309189535;
    double rev = th * INV2PI;
    double fr = rev - rint(rev);                 // [-0.5, 0.5]
    float x = (float)fr * 6.283185307179586f;
    sn = (double)__sinf(x);
    cs = (double)__cosf(x);
}

// ---- K1: controls passthrough + per-block rigid-motion aggregates -------
// Aggregate of block p (entry angle unknown): Theta = sum dth,
// A = sum s*cos(phi_local), B = sum s*sin(phi_local).

__global__ void __launch_bounds__(BLOCK, 8) k_agg(
    const float4* __restrict__ ctrl4, float4* __restrict__ out4,
    double* __restrict__ aggTh, double* __restrict__ aggA,
    double* __restrict__ aggB) {
    __shared__ double sw[NWAVE];
    const int b = blockIdx.x, t = threadIdx.x;
    const int f = b * BLOCK + t;  // one float4 (= 2 control rows) per thread

    float4 c4 = (f < NF4) ? ctrl4[f] : make_float4(0.f, 0.f, 0.f, 0.f);
    if (f < NF4) out4[f] = c4;  // controls passthrough output

    const double dth0 = 10.0 * (double)c4.y;
    const double dth1 = 10.0 * (double)c4.w;
    double thTot;
    const double thb = blockScanEx(dth0 + dth1, sw, &thTot);

    double cs0, sn0, cs1, sn1;
    ftrig(thb, cs0, sn0);
    ftrig(thb + dth0, cs1, sn1);
    const double s0 = fabs((double)c4.x), s1 = fabs((double)c4.z);
    const double la = s0 * cs0 + s1 * cs1;
    const double lb = s0 * sn0 + s1 * sn1;

    const double A = blockSum(la, sw);
    const double B = blockSum(lb, sw);
    if (t == 0) {
        aggTh[b] = thTot;
        aggA[b]  = A;
        aggB[b]  = B;
    }
}

// ---- K2: compose aggregates, redo local scan, write traj ----------------

__global__ void __launch_bounds__(BLOCK, 8) k_out(
    const float4* __restrict__ ctrl4, const float* __restrict__ sp,
    const double* __restrict__ aggTh, const double* __restrict__ aggA,
    const double* __restrict__ aggB, float* __restrict__ traj) {
    __shared__ double sw[NWAVE];
    const int b = blockIdx.x, t = threadIdx.x;
    const int f = b * BLOCK + t;

    // issue the controls load immediately; it overlaps the compose phase
    float4 c4 = (f < NF4) ? ctrl4[f] : make_float4(0.f, 0.f, 0.f, 0.f);

    const double x0 = (double)sp[0], y0 = (double)sp[1], th0 = (double)sp[2];

    // -- phase B: entry state (Xin, Yin, psi) from predecessor aggregates --
    double pTh = 0.0, pA = 0.0, pB = 0.0;
    if (t < NB) {
        pTh = aggTh[t];
        pA  = aggA[t];
        pB  = aggB[t];
    }
    double aggTot;
    const double excl = blockScanEx(pTh, sw, &aggTot);  // theta entry of agg t

    double cx = 0.0, cy = 0.0, mth = 0.0;
    if (t < b) {
        double cs, sn;
        ftrig(th0 + excl, cs, sn);
        cx  = cs * pA - sn * pB;
        cy  = sn * pA + cs * pB;
        mth = pTh;
    }
    const double psi = th0 + blockSum(mth, sw);  // my block's entry angle
    const double Xin = x0 + blockSum(cx, sw);
    const double Yin = y0 + blockSum(cy, sw);
    double cps, sps;
    ftrig(psi, cps, sps);

    // -- phase A redo: local scans + final writes --
    const double dth0 = 10.0 * (double)c4.y;
    const double dth1 = 10.0 * (double)c4.w;
    double thTot;
    const double thb = blockScanEx(dth0 + dth1, sw, &thTot);

    double cs0, sn0, cs1, sn1;
    ftrig(thb, cs0, sn0);
    ftrig(thb + dth0, cs1, sn1);
    const double s0 = fabs((double)c4.x), s1 = fabs((double)c4.z);
    const double a0 = s0 * cs0, b0 = s0 * sn0;
    const double a1 = s1 * cs1, b1 = s1 * sn1;

    double aTot, bTot;
    const double Aex = blockScanEx(a0 + a1, sw, &aTot);
    const double Bex = blockScanEx(b0 + b1, sw, &bTot);

    const double A1 = Aex + a0, B1 = Bex + b0;
    const double A2 = A1 + a1,  B2 = B1 + b1;

    const long i0 = (long)b * CHUNK + 2L * t;  // global element index of 1st owned row
    if (i0 < T_STEPS) {
        float* row = traj + 3 * (i0 + 1);
        row[0] = (float)(Xin + cps * A1 - sps * B1);
        row[1] = (float)(Yin + sps * A1 + cps * B1);
        row[2] = (float)(psi + thb + dth0);
    }
    if (i0 + 1 < T_STEPS) {
        float* row = traj + 3 * (i0 + 2);
        row[0] = (float)(Xin + cps * A2 - sps * B2);
        row[1] = (float)(Yin + sps * A2 + cps * B2);
        row[2] = (float)(psi + thb + dth0 + dth1);
    }
    if (b == 0 && t == 0) {
        traj[0] = sp[0];
        traj[1] = sp[1];
        traj[2] = sp[2];
    }
}

// ---- launch --------------------------------------------------------------

extern "C" void kernel_launch(void* const* d_in, const int* in_sizes, int n_in,
                              void* d_out, int out_size, void* d_ws, size_t ws_size,
                              hipStream_t stream) {
    const float*  start_pose = (const float*)d_in[0];
    const float4* ctrl4      = (const float4*)d_in[1];

    float*  out  = (float*)d_out;
    float4* out4 = (float4*)out;                 // controls passthrough
    float*  traj = out + 2 * (long)T_STEPS;      // (T+1, 3)

    double* aggTh = (double*)d_ws;
    double* aggA  = aggTh + NB;
    double* aggB  = aggA + NB;

    hipLaunchKernelGGL(k_agg, dim3(NB), dim3(BLOCK), 0, stream,
                       ctrl4, out4, aggTh, aggA, aggB);
    hipLaunchKernelGGL(k_out, dim3(NB), dim3(BLOCK), 0, stream,
                       ctrl4, start_pose, aggTh, aggA, aggB, traj);
}

// Round 6
// 64.234 us; speedup vs baseline: 1.3045x; 1.3045x over previous
//
#include <hip/hip_runtime.h>
#include <math.h>

#define T_STEPS 1000000
#define BLOCK 1024
#define ITEMS 2
#define CHUNK (BLOCK * ITEMS)               // 2048
#define NB ((T_STEPS + CHUNK - 1) / CHUNK)  // 489
#define NF4 (T_STEPS / 2)                   // 500000 float4 of controls
#define NWAVE (BLOCK / 64)                  // 16

// ---- wave/block scan helpers (fp64, shfl + 16-partial LDS) --------------

__device__ __forceinline__ double waveScanIncl(double v) {
#pragma unroll
    for (int off = 1; off < 64; off <<= 1) {
        double x = __shfl_up(v, off, 64);
        if ((threadIdx.x & 63) >= off) v += x;
    }
    return v;
}

// exclusive prefix over the block's per-thread values; *tot = block total
__device__ __forceinline__ double blockScanEx(double v, double* sw, double* tot) {
    const int lane = threadIdx.x & 63, w = threadIdx.x >> 6;
    double inc = waveScanIncl(v);
    if (lane == 63) sw[w] = inc;
    __syncthreads();
    double woff = 0.0, T = 0.0;
#pragma unroll
    for (int i = 0; i < NWAVE; ++i) {
        double x = sw[i];
        T += x;
        if (i < w) woff += x;
    }
    __syncthreads();
    *tot = T;
    return woff + inc - v;
}

__device__ __forceinline__ double blockSum(double v, double* sw) {
#pragma unroll
    for (int off = 32; off > 0; off >>= 1) v += __shfl_xor(v, off, 64);
    const int lane = threadIdx.x & 63, w = threadIdx.x >> 6;
    if (lane == 0) sw[w] = v;
    __syncthreads();
    double r = 0.0;
#pragma unroll
    for (int i = 0; i < NWAVE; ++i) r += sw[i];
    __syncthreads();
    return r;
}

// fp64 range reduction -> HW v_sin_f32/v_cos_f32 (abs err ~1e-6)
__device__ __forceinline__ void ftrig(double th, double& cs, double& sn) {
    const double INV2PI = 0.15915494309189535;
    double rev = th * INV2PI;
    double fr = rev - rint(rev);                 // [-0.5, 0.5]
    float x = (float)fr * 6.283185307179586f;
    sn = (double)__sinf(x);
    cs = (double)__cosf(x);
}

// ---- K1: controls passthrough + per-block rigid-motion aggregates -------
// Aggregate of block p (entry angle unknown): Theta = sum dth,
// A = sum s*cos(phi_local), B = sum s*sin(phi_local).
// launch_bounds(1024,4): VGPR cap 128 -> no scratch spills (R5 lesson:
// (1024,8) capped VGPR at 32 and spilled ~200 MB of scratch traffic).

__global__ void __launch_bounds__(BLOCK, 4) k_agg(
    const float4* __restrict__ ctrl4, float4* __restrict__ out4,
    double* __restrict__ aggTh, double* __restrict__ aggA,
    double* __restrict__ aggB) {
    __shared__ double sw[NWAVE];
    const int b = blockIdx.x, t = threadIdx.x;
    const int f = b * BLOCK + t;  // one float4 (= 2 control rows) per thread

    float4 c4 = (f < NF4) ? ctrl4[f] : make_float4(0.f, 0.f, 0.f, 0.f);
    if (f < NF4) out4[f] = c4;  // controls passthrough output

    const double dth0 = 10.0 * (double)c4.y;
    const double dth1 = 10.0 * (double)c4.w;
    double thTot;
    const double thb = blockScanEx(dth0 + dth1, sw, &thTot);

    double cs0, sn0, cs1, sn1;
    ftrig(thb, cs0, sn0);
    ftrig(thb + dth0, cs1, sn1);
    const double s0 = fabs((double)c4.x), s1 = fabs((double)c4.z);
    const double la = s0 * cs0 + s1 * cs1;
    const double lb = s0 * sn0 + s1 * sn1;

    const double A = blockSum(la, sw);
    const double B = blockSum(lb, sw);
    if (t == 0) {
        aggTh[b] = thTot;
        aggA[b]  = A;
        aggB[b]  = B;
    }
}

// ---- K2: compose aggregates, redo local scan, write traj ----------------

__global__ void __launch_bounds__(BLOCK, 4) k_out(
    const float4* __restrict__ ctrl4, const float* __restrict__ sp,
    const double* __restrict__ aggTh, const double* __restrict__ aggA,
    const double* __restrict__ aggB, float* __restrict__ traj) {
    __shared__ double sw[NWAVE];
    const int b = blockIdx.x, t = threadIdx.x;
    const int f = b * BLOCK + t;

    // issue the controls load immediately; it overlaps the compose phase
    float4 c4 = (f < NF4) ? ctrl4[f] : make_float4(0.f, 0.f, 0.f, 0.f);

    const double x0 = (double)sp[0], y0 = (double)sp[1], th0 = (double)sp[2];

    // -- phase B: entry state (Xin, Yin, psi) from predecessor aggregates --
    double pTh = 0.0, pA = 0.0, pB = 0.0;
    if (t < NB) {
        pTh = aggTh[t];
        pA  = aggA[t];
        pB  = aggB[t];
    }
    double aggTot;
    const double excl = blockScanEx(pTh, sw, &aggTot);  // theta entry of agg t

    double cx = 0.0, cy = 0.0, mth = 0.0;
    if (t < b) {
        double cs, sn;
        ftrig(th0 + excl, cs, sn);
        cx  = cs * pA - sn * pB;
        cy  = sn * pA + cs * pB;
        mth = pTh;
    }
    const double psi = th0 + blockSum(mth, sw);  // my block's entry angle
    const double Xin = x0 + blockSum(cx, sw);
    const double Yin = y0 + blockSum(cy, sw);
    double cps, sps;
    ftrig(psi, cps, sps);

    // -- phase A redo: local scans + final writes --
    const double dth0 = 10.0 * (double)c4.y;
    const double dth1 = 10.0 * (double)c4.w;
    double thTot;
    const double thb = blockScanEx(dth0 + dth1, sw, &thTot);

    double cs0, sn0, cs1, sn1;
    ftrig(thb, cs0, sn0);
    ftrig(thb + dth0, cs1, sn1);
    const double s0 = fabs((double)c4.x), s1 = fabs((double)c4.z);
    const double a0 = s0 * cs0, b0 = s0 * sn0;
    const double a1 = s1 * cs1, b1 = s1 * sn1;

    double aTot, bTot;
    const double Aex = blockScanEx(a0 + a1, sw, &aTot);
    const double Bex = blockScanEx(b0 + b1, sw, &bTot);

    const double A1 = Aex + a0, B1 = Bex + b0;
    const double A2 = A1 + a1,  B2 = B1 + b1;

    // contiguous 6-float store region per thread (rows i0+1, i0+2)
    const long i0 = (long)b * CHUNK + 2L * t;
    if (i0 < T_STEPS) {
        float* p = traj + 3 * (i0 + 1);
        p[0] = (float)(Xin + cps * A1 - sps * B1);
        p[1] = (float)(Yin + sps * A1 + cps * B1);
        p[2] = (float)(psi + thb + dth0);
        p[3] = (float)(Xin + cps * A2 - sps * B2);
        p[4] = (float)(Yin + sps * A2 + cps * B2);
        p[5] = (float)(psi + thb + dth0 + dth1);
    }
    if (b == 0 && t == 0) {
        traj[0] = sp[0];
        traj[1] = sp[1];
        traj[2] = sp[2];
    }
}

// ---- launch --------------------------------------------------------------

extern "C" void kernel_launch(void* const* d_in, const int* in_sizes, int n_in,
                              void* d_out, int out_size, void* d_ws, size_t ws_size,
                              hipStream_t stream) {
    const float*  start_pose = (const float*)d_in[0];
    const float4* ctrl4      = (const float4*)d_in[1];

    float*  out  = (float*)d_out;
    float4* out4 = (float4*)out;                 // controls passthrough
    float*  traj = out + 2 * (long)T_STEPS;      // (T+1, 3)

    double* aggTh = (double*)d_ws;
    double* aggA  = aggTh + NB;
    double* aggB  = aggA + NB;

    hipLaunchKernelGGL(k_agg, dim3(NB), dim3(BLOCK), 0, stream,
                       ctrl4, out4, aggTh, aggA, aggB);
    hipLaunchKernelGGL(k_out, dim3(NB), dim3(BLOCK), 0, stream,
                       ctrl4, start_pose, aggTh, aggA, aggB, traj);
}

// Round 7
// 29.807 us; speedup vs baseline: 2.8113x; 2.1550x over previous
//
#include <hip/hip_runtime.h>
#include <math.h>

#define T_STEPS 1000000
#define BLOCK 256
#define CHUNK (2 * BLOCK)                   // 512 elements (1 float4 / thread)
#define NF4 (T_STEPS / 2)                   // 500000 float4 of controls
#define NB ((NF4 + BLOCK - 1) / BLOCK)      // 1954 segments == grid blocks
#define NWAVE (BLOCK / 64)                  // 4
#define PER ((NB + BLOCK - 1) / BLOCK)      // 8 aggregates/thread in compose

// ---- wave/block scan helpers (fp64, shfl + 4-partial LDS) ---------------

__device__ __forceinline__ double waveScanIncl(double v) {
#pragma unroll
    for (int off = 1; off < 64; off <<= 1) {
        double x = __shfl_up(v, off, 64);
        if ((threadIdx.x & 63) >= off) v += x;
    }
    return v;
}

// exclusive prefix over the block's per-thread values; *tot = block total
__device__ __forceinline__ double blockScanEx(double v, double* sw, double* tot) {
    const int lane = threadIdx.x & 63, w = threadIdx.x >> 6;
    double inc = waveScanIncl(v);
    if (lane == 63) sw[w] = inc;
    __syncthreads();
    double w0 = sw[0], w1 = sw[1], w2 = sw[2], w3 = sw[3];
    __syncthreads();
    *tot = w0 + w1 + w2 + w3;
    double woff = (w > 0 ? w0 : 0.0) + (w > 1 ? w1 : 0.0) + (w > 2 ? w2 : 0.0);
    return woff + inc - v;
}

__device__ __forceinline__ double blockSum(double v, double* sw) {
#pragma unroll
    for (int off = 32; off > 0; off >>= 1) v += __shfl_xor(v, off, 64);
    const int lane = threadIdx.x & 63, w = threadIdx.x >> 6;
    if (lane == 0) sw[w] = v;
    __syncthreads();
    double r = sw[0] + sw[1] + sw[2] + sw[3];
    __syncthreads();
    return r;
}

// fp64 range reduction -> HW v_sin_f32/v_cos_f32 (abs err ~1e-6)
__device__ __forceinline__ void ftrig(double th, double& cs, double& sn) {
    const double INV2PI = 0.15915494309189535;
    double rev = th * INV2PI;
    double fr = rev - rint(rev);                 // [-0.5, 0.5]
    float x = (float)fr * 6.283185307179586f;
    sn = (double)__sinf(x);
    cs = (double)__cosf(x);
}

// ---- K1: controls passthrough + per-segment rigid-motion aggregates -----
// Aggregate of segment p (entry angle unknown): Theta = sum dth,
// A = sum s*cos(phi_local), B = sum s*sin(phi_local).
// 256-thread blocks: small live set, no spills (R5/R6 lesson: 1024-thread
// blocks force a VGPR cap that spills ~100+ MB of scratch traffic).

__global__ void __launch_bounds__(BLOCK, 4) k_agg(
    const float4* __restrict__ ctrl4, float4* __restrict__ out4,
    double* __restrict__ aggTh, double* __restrict__ aggA,
    double* __restrict__ aggB) {
    __shared__ double sw[NWAVE];
    const int b = blockIdx.x, t = threadIdx.x;
    const int f = b * BLOCK + t;  // one float4 (= 2 control rows) per thread

    float4 c4 = (f < NF4) ? ctrl4[f] : make_float4(0.f, 0.f, 0.f, 0.f);
    if (f < NF4) out4[f] = c4;  // controls passthrough output

    const double dth0 = 10.0 * (double)c4.y;
    const double dth1 = 10.0 * (double)c4.w;
    double thTot;
    const double thb = blockScanEx(dth0 + dth1, sw, &thTot);

    double cs0, sn0, cs1, sn1;
    ftrig(thb, cs0, sn0);
    ftrig(thb + dth0, cs1, sn1);
    const double s0 = fabs((double)c4.x), s1 = fabs((double)c4.z);
    const double la = s0 * cs0 + s1 * cs1;
    const double lb = s0 * sn0 + s1 * sn1;

    const double A = blockSum(la, sw);
    const double B = blockSum(lb, sw);
    if (t == 0) {
        aggTh[b] = thTot;
        aggA[b]  = A;
        aggB[b]  = B;
    }
}

// ---- K2: compose prefix aggregates, redo local scan, write traj ---------

__global__ void __launch_bounds__(BLOCK, 4) k_out(
    const float4* __restrict__ ctrl4, const float* __restrict__ sp,
    const double* __restrict__ aggTh, const double* __restrict__ aggA,
    const double* __restrict__ aggB, float* __restrict__ traj) {
    __shared__ double sw[NWAVE];
    const int b = blockIdx.x, t = threadIdx.x;
    const int f = b * BLOCK + t;

    // issue the controls load immediately; it overlaps the compose phase
    float4 c4 = (f < NF4) ? ctrl4[f] : make_float4(0.f, 0.f, 0.f, 0.f);

    const double x0 = (double)sp[0], y0 = (double)sp[1], th0 = (double)sp[2];

    // -- phase B: entry state (Xin, Yin, psi) from predecessor aggregates --
    double pTh[PER];
    double lsum = 0.0;
#pragma unroll
    for (int k = 0; k < PER; ++k) {
        int p = t * PER + k;
        pTh[k] = (p < NB) ? aggTh[p] : 0.0;
        lsum += pTh[k];
    }
    double aggTot;
    const double excl = blockScanEx(lsum, sw, &aggTot);  // theta entry of slot t*PER

    double cx = 0.0, cy = 0.0, mth = 0.0;
    {
        double run = th0 + excl;
#pragma unroll
        for (int k = 0; k < PER; ++k) {
            int p = t * PER + k;
            if (p < b) {
                double cs, sn;
                ftrig(run, cs, sn);
                const double pa = aggA[p], pb = aggB[p];  // L2-hot, loaded late
                cx += cs * pa - sn * pb;
                cy += sn * pa + cs * pb;
                mth += pTh[k];
            }
            run += pTh[k];
        }
    }
    const double psi = th0 + blockSum(mth, sw);  // my segment's entry angle
    const double Xin = x0 + blockSum(cx, sw);
    const double Yin = y0 + blockSum(cy, sw);
    double cps, sps;
    ftrig(psi, cps, sps);

    // -- phase A redo: local scans + final writes --
    const double dth0 = 10.0 * (double)c4.y;
    const double dth1 = 10.0 * (double)c4.w;
    double thTot;
    const double thb = blockScanEx(dth0 + dth1, sw, &thTot);

    double cs0, sn0, cs1, sn1;
    ftrig(thb, cs0, sn0);
    ftrig(thb + dth0, cs1, sn1);
    const double s0 = fabs((double)c4.x), s1 = fabs((double)c4.z);
    const double a0 = s0 * cs0, b0 = s0 * sn0;
    const double a1 = s1 * cs1, b1 = s1 * sn1;

    double aTot, bTot;
    const double Aex = blockScanEx(a0 + a1, sw, &aTot);
    const double Bex = blockScanEx(b0 + b1, sw, &bTot);

    const double A1 = Aex + a0, B1 = Bex + b0;
    const double A2 = A1 + a1,  B2 = B1 + b1;

    // contiguous 6-float store region per thread (rows i0+1, i0+2)
    const long i0 = (long)b * CHUNK + 2L * t;
    if (i0 < T_STEPS) {
        float* p = traj + 3 * (i0 + 1);
        p[0] = (float)(Xin + cps * A1 - sps * B1);
        p[1] = (float)(Yin + sps * A1 + cps * B1);
        p[2] = (float)(psi + thb + dth0);
        p[3] = (float)(Xin + cps * A2 - sps * B2);
        p[4] = (float)(Yin + sps * A2 + cps * B2);
        p[5] = (float)(psi + thb + dth0 + dth1);
    }
    if (b == 0 && t == 0) {
        traj[0] = sp[0];
        traj[1] = sp[1];
        traj[2] = sp[2];
    }
}

// ---- launch --------------------------------------------------------------

extern "C" void kernel_launch(void* const* d_in, const int* in_sizes, int n_in,
                              void* d_out, int out_size, void* d_ws, size_t ws_size,
                              hipStream_t stream) {
    const float*  start_pose = (const float*)d_in[0];
    const float4* ctrl4      = (const float4*)d_in[1];

    float*  out  = (float*)d_out;
    float4* out4 = (float4*)out;                 // controls passthrough
    float*  traj = out + 2 * (long)T_STEPS;      // (T+1, 3)

    double* aggTh = (double*)d_ws;
    double* aggA  = aggTh + NB;
    double* aggB  = aggA + NB;

    hipLaunchKernelGGL(k_agg, dim3(NB), dim3(BLOCK), 0, stream,
                       ctrl4, out4, aggTh, aggA, aggB);
    hipLaunchKernelGGL(k_out, dim3(NB), dim3(BLOCK), 0, stream,
                       ctrl4, start_pose, aggTh, aggA, aggB, traj);
}

// Round 8
// 25.472 us; speedup vs baseline: 3.2897x; 1.1702x over previous
//
#include <hip/hip_runtime.h>
#include <math.h>

#define T_STEPS 1000000
#define BLOCK 256
#define CHUNK (2 * BLOCK)                   // 512 elements (1 float4 / thread)
#define NF4 (T_STEPS / 2)                   // 500000 float4 of controls
#define NB ((NF4 + BLOCK - 1) / BLOCK)      // 1954 segments == grid blocks
#define NWAVE (BLOCK / 64)                  // 4

#define MIDBLOCK 1024
#define MIDWAVE (MIDBLOCK / 64)             // 16
#define MPER ((NB + MIDBLOCK - 1) / MIDBLOCK)  // 2 aggregates/thread in k_mid

// ---- scan helpers (fp64, shfl + LDS partials), templated on wave count --

__device__ __forceinline__ double waveScanIncl(double v) {
#pragma unroll
    for (int off = 1; off < 64; off <<= 1) {
        double x = __shfl_up(v, off, 64);
        if ((threadIdx.x & 63) >= off) v += x;
    }
    return v;
}

template <int NW>
__device__ __forceinline__ double blockScanEx(double v, double* sw, double* tot) {
    const int lane = threadIdx.x & 63, w = threadIdx.x >> 6;
    double inc = waveScanIncl(v);
    if (lane == 63) sw[w] = inc;
    __syncthreads();
    double woff = 0.0, T = 0.0;
#pragma unroll
    for (int i = 0; i < NW; ++i) {
        double x = sw[i];
        T += x;
        if (i < w) woff += x;
    }
    __syncthreads();
    *tot = T;
    return woff + inc - v;
}

// fp64 range reduction -> HW v_sin_f32/v_cos_f32 (abs err ~1e-6)
__device__ __forceinline__ void ftrig(double th, double& cs, double& sn) {
    const double INV2PI = 0.15915494309189535;
    double rev = th * INV2PI;
    double fr = rev - rint(rev);                 // [-0.5, 0.5]
    float x = (float)fr * 6.283185307179586f;
    sn = (double)__sinf(x);
    cs = (double)__cosf(x);
}

// ---- K1: controls passthrough + per-segment rigid-motion aggregates -----
// Aggregate of segment p (entry angle unknown): Theta = sum dth,
// A = sum s*cos(phi_local), B = sum s*sin(phi_local).

__global__ void __launch_bounds__(BLOCK, 4) k_agg(
    const float4* __restrict__ ctrl4, float4* __restrict__ out4,
    double* __restrict__ aggTh, double* __restrict__ aggA,
    double* __restrict__ aggB) {
    __shared__ double sw[NWAVE];
    const int b = blockIdx.x, t = threadIdx.x;
    const int f = b * BLOCK + t;  // one float4 (= 2 control rows) per thread

    float4 c4 = (f < NF4) ? ctrl4[f] : make_float4(0.f, 0.f, 0.f, 0.f);
    if (f < NF4) out4[f] = c4;  // controls passthrough output

    const double dth0 = 10.0 * (double)c4.y;
    const double dth1 = 10.0 * (double)c4.w;
    double thTot;
    const double thb = blockScanEx<NWAVE>(dth0 + dth1, sw, &thTot);

    double cs0, sn0, cs1, sn1;
    ftrig(thb, cs0, sn0);
    ftrig(thb + dth0, cs1, sn1);
    const double s0 = fabs((double)c4.x), s1 = fabs((double)c4.z);
    const double la = s0 * cs0 + s1 * cs1;
    const double lb = s0 * sn0 + s1 * sn1;

    // block totals via scan (reuse): tot comes back from blockScanEx
    double aTot, bTot;
    (void)blockScanEx<NWAVE>(la, sw, &aTot);
    (void)blockScanEx<NWAVE>(lb, sw, &bTot);
    if (t == 0) {
        aggTh[b] = thTot;
        aggA[b]  = aTot;
        aggB[b]  = bTot;
    }
}

// ---- K_mid: ONE block scans all segment aggregates -> entry states ------
// entry[p] = (Xin, Yin, psi) at the first element of segment p.
// Total work is O(NB): one ftrig per aggregate.

__global__ void __launch_bounds__(MIDBLOCK, 4) k_mid(
    const float* __restrict__ sp,
    const double* __restrict__ aggTh, const double* __restrict__ aggA,
    const double* __restrict__ aggB,
    double* __restrict__ entX, double* __restrict__ entY,
    double* __restrict__ entPsi) {
    __shared__ double sw[MIDWAVE];
    const int t = threadIdx.x;
    const double x0 = (double)sp[0], y0 = (double)sp[1], th0 = (double)sp[2];

    // thread owns MPER contiguous aggregates (scan order)
    double pTh[MPER], pA[MPER], pB[MPER];
    double lth = 0.0;
#pragma unroll
    for (int k = 0; k < MPER; ++k) {
        int p = t * MPER + k;
        if (p < NB) {
            pTh[k] = aggTh[p];
            pA[k]  = aggA[p];
            pB[k]  = aggB[p];
        } else {
            pTh[k] = pA[k] = pB[k] = 0.0;
        }
        lth += pTh[k];
    }
    double thTot;
    const double thEx = blockScanEx<MIDWAVE>(lth, sw, &thTot);

    // rotate each aggregate's displacement into world frame
    double tx[MPER], ty[MPER], psi[MPER];
    double lx = 0.0, ly = 0.0;
    {
        double run = th0 + thEx;  // entry angle of aggregate t*MPER
#pragma unroll
        for (int k = 0; k < MPER; ++k) {
            psi[k] = run;
            double cs, sn;
            ftrig(run, cs, sn);
            tx[k] = cs * pA[k] - sn * pB[k];
            ty[k] = sn * pA[k] + cs * pB[k];
            lx += tx[k];
            ly += ty[k];
            run += pTh[k];
        }
    }
    double xTot, yTot;
    double xEx = blockScanEx<MIDWAVE>(lx, sw, &xTot);
    double yEx = blockScanEx<MIDWAVE>(ly, sw, &yTot);

    double rx = x0 + xEx, ry = y0 + yEx;
#pragma unroll
    for (int k = 0; k < MPER; ++k) {
        int p = t * MPER + k;
        if (p < NB) {
            entX[p]   = rx;
            entY[p]   = ry;
            entPsi[p] = psi[k];
        }
        rx += tx[k];
        ry += ty[k];
    }
}

// ---- K_out: O(1) entry-state read, local scan, write traj ---------------

__global__ void __launch_bounds__(BLOCK, 4) k_out(
    const float4* __restrict__ ctrl4, const float* __restrict__ sp,
    const double* __restrict__ entX, const double* __restrict__ entY,
    const double* __restrict__ entPsi, float* __restrict__ traj) {
    __shared__ double sw[NWAVE];
    __shared__ double sent[3];
    const int b = blockIdx.x, t = threadIdx.x;
    const int f = b * BLOCK + t;

    float4 c4 = (f < NF4) ? ctrl4[f] : make_float4(0.f, 0.f, 0.f, 0.f);
    if (t == 0) {
        sent[0] = entX[b];
        sent[1] = entY[b];
        sent[2] = entPsi[b];
    }

    const double dth0 = 10.0 * (double)c4.y;
    const double dth1 = 10.0 * (double)c4.w;
    double thTot;
    const double thb = blockScanEx<NWAVE>(dth0 + dth1, sw, &thTot);  // syncthreads covers sent

    double cs0, sn0, cs1, sn1;
    ftrig(thb, cs0, sn0);
    ftrig(thb + dth0, cs1, sn1);
    const double s0 = fabs((double)c4.x), s1 = fabs((double)c4.z);
    const double a0 = s0 * cs0, b0 = s0 * sn0;
    const double a1 = s1 * cs1, b1 = s1 * sn1;

    double aTot, bTot;
    const double Aex = blockScanEx<NWAVE>(a0 + a1, sw, &aTot);
    const double Bex = blockScanEx<NWAVE>(b0 + b1, sw, &bTot);

    const double Xin = sent[0], Yin = sent[1], psi = sent[2];
    double cps, sps;
    ftrig(psi, cps, sps);

    const double A1 = Aex + a0, B1 = Bex + b0;
    const double A2 = A1 + a1,  B2 = B1 + b1;

    // contiguous 6-float store region per thread (rows i0+1, i0+2)
    const long i0 = (long)b * CHUNK + 2L * t;
    if (i0 < T_STEPS) {
        float* p = traj + 3 * (i0 + 1);
        p[0] = (float)(Xin + cps * A1 - sps * B1);
        p[1] = (float)(Yin + sps * A1 + cps * B1);
        p[2] = (float)(psi + thb + dth0);
        p[3] = (float)(Xin + cps * A2 - sps * B2);
        p[4] = (float)(Yin + sps * A2 + cps * B2);
        p[5] = (float)(psi + thb + dth0 + dth1);
    }
    if (b == 0 && t == 0) {
        traj[0] = sp[0];
        traj[1] = sp[1];
        traj[2] = sp[2];
    }
}

// ---- launch --------------------------------------------------------------

extern "C" void kernel_launch(void* const* d_in, const int* in_sizes, int n_in,
                              void* d_out, int out_size, void* d_ws, size_t ws_size,
                              hipStream_t stream) {
    const float*  start_pose = (const float*)d_in[0];
    const float4* ctrl4      = (const float4*)d_in[1];

    float*  out  = (float*)d_out;
    float4* out4 = (float4*)out;                 // controls passthrough
    float*  traj = out + 2 * (long)T_STEPS;      // (T+1, 3)

    double* aggTh  = (double*)d_ws;
    double* aggA   = aggTh + NB;
    double* aggB   = aggA + NB;
    double* entX   = aggB + NB;
    double* entY   = entX + NB;
    double* entPsi = entY + NB;

    hipLaunchKernelGGL(k_agg, dim3(NB), dim3(BLOCK), 0, stream,
                       ctrl4, out4, aggTh, aggA, aggB);
    hipLaunchKernelGGL(k_mid, dim3(1), dim3(MIDBLOCK), 0, stream,
                       start_pose, aggTh, aggA, aggB, entX, entY, entPsi);
    hipLaunchKernelGGL(k_out, dim3(NB), dim3(BLOCK), 0, stream,
                       ctrl4, start_pose, entX, entY, entPsi, traj);
}